// Round 4
// baseline (24.841 us; speedup 1.0000x reference)
//
#include <hip/hip_runtime.h>
#include <math.h>

#define HDIM 224
#define WDIM 224
#define OH 220
#define OW 220
#define NCOL 30
#define SROWS 20               // output rows per strip (220 = 11*20, exact cover)
#define NSTRIP 11
#define LROWS (SROWS + 4)      // 24 input rows per strip
#define NORM_INV (1.0f / (25.0f * 768.0f))

__device__ __forceinline__ float4 ld4(const float* p) {
    return *reinterpret_cast<const float4*>(p);
}

__global__ __launch_bounds__(64) void rgb_conv2d_kernel(
    const float* __restrict__ in,   // [B,3,224,224]
    const float* __restrict__ wt,   // [30,3,5,5] (color constant over window)
    float* __restrict__ out)        // [B,30,220,220]
{
    // One wave per (image b, color c, row-strip s). gid&7 == b so all blocks
    // of an image land on one XCD (round-robin heuristic) -> input L2-resident.
    const int gid  = blockIdx.x;
    const int b    = gid & 7;
    const int k    = gid >> 3;          // 0..329
    const int c    = k / NSTRIP;
    const int s    = k - c * NSTRIP;
    const int lane = threadIdx.x;       // 0..63

    const bool comp = lane < 56;        // lanes computing distances (cols 4l..4l+3)
    const bool st   = lane < 55;        // lanes storing outputs   (cols 4l..4l+3 <= 219)

    const float* pr = in + (size_t)b * 3 * HDIM * WDIM
                    + (size_t)(SROWS * s) * WDIM + 4 * lane;
    const float* pg = pr + HDIM * WDIM;
    const float* pb = pr + 2 * HDIM * WDIM;
    float* ob = out + ((size_t)(b * NCOL + c) * OH + SROWS * s) * OW + 4 * lane;

    const float R2 = wt[c * 75 +  0] * 255.0f;
    const float G2 = wt[c * 75 + 25] * 255.0f;
    const float B2 = wt[c * 75 + 50] * 255.0f;
    // d^2 = cR*dR^2 + (2dG)^2 + cB*dB^2 + eps; x255 folded into fma constants
    const float kR  = fmaf(R2, 1.0f / 512.0f, 2.0f);
    const float CC  = 4.0f + 255.0f / 256.0f;
    const float mR2 = -R2, mG2 = -2.0f * G2, mB2 = -B2;

    auto dist = [&](float xr, float xg, float xb) -> float {
        float dR  = fmaf(xr, 255.0f, mR2);
        float cR  = fmaf(xr, 255.0f / 512.0f, kR);
        float cB  = CC - cR;
        float dG2 = fmaf(xg, 510.0f, mG2);
        float dB  = fmaf(xb, 255.0f, mB2);
        float t   = fmaf(cR * dR, dR, 1e-8f);
        t = fmaf(dG2, dG2, t);
        t = fmaf(cB * dB, dB, t);
        return __builtin_amdgcn_sqrtf(t);
    };

    // 5-deep register ring of horizontal 5-sums, rotated by register rename.
    float4 h0, h1, h2, h3, h4;

    for (int r = 0; r < LROWS; ++r) {
        float4 dq = make_float4(0.f, 0.f, 0.f, 0.f);
        if (comp) {
            float4 Pr = ld4(pr + r * WDIM);
            float4 Pg = ld4(pg + r * WDIM);
            float4 Pb = ld4(pb + r * WDIM);
            dq.x = dist(Pr.x, Pg.x, Pb.x);
            dq.y = dist(Pr.y, Pg.y, Pb.y);
            dq.z = dist(Pr.z, Pg.z, Pb.z);
            dq.w = dist(Pr.w, Pg.w, Pb.w);
        }
        // Neighbor lane's 4 distances (cols 4l+4..4l+7)
        float nx = __shfl_down(dq.x, 1, 64);
        float ny = __shfl_down(dq.y, 1, 64);
        float nz = __shfl_down(dq.z, 1, 64);
        float nw = __shfl_down(dq.w, 1, 64);

        // Horizontal 5-sums for output cols 4l..4l+3
        float4 hn;
        hn.x = ((dq.x + dq.y) + (dq.z + dq.w)) + nx;
        hn.y = hn.x - dq.x + ny;
        hn.z = hn.y - dq.y + nz;
        hn.w = hn.z - dq.z + nw;

        h0 = h1; h1 = h2; h2 = h3; h3 = h4; h4 = hn;   // rotate ring

        if (r >= 4 && st) {
            float4 o;
            o.x = (((h0.x + h1.x) + (h2.x + h3.x)) + h4.x) * NORM_INV;
            o.y = (((h0.y + h1.y) + (h2.y + h3.y)) + h4.y) * NORM_INV;
            o.z = (((h0.z + h1.z) + (h2.z + h3.z)) + h4.z) * NORM_INV;
            o.w = (((h0.w + h1.w) + (h2.w + h3.w)) + h4.w) * NORM_INV;
            *reinterpret_cast<float4*>(ob + (size_t)(r - 4) * OW) = o;
        }
    }
}

extern "C" void kernel_launch(void* const* d_in, const int* in_sizes, int n_in,
                              void* d_out, int out_size, void* d_ws, size_t ws_size,
                              hipStream_t stream) {
    const float* in = (const float*)d_in[0];
    const float* wt = (const float*)d_in[1];
    float* out = (float*)d_out;

    const int B = in_sizes[0] / (3 * HDIM * WDIM);       // 8
    const int nblocks = B * NCOL * NSTRIP;               // 2640 single-wave blocks
    rgb_conv2d_kernel<<<dim3(nblocks), dim3(64), 0, stream>>>(in, wt, out);
}